// Round 8
// baseline (801.848 us; speedup 1.0000x reference)
//
#include <hip/hip_runtime.h>
#include <hip/hip_fp16.h>
#include <math.h>

#define NN 100000
#define EE 1600000
#define HH 64
#define LL 8
#define NBLK ((NN + 1023) / 1024)

// binned scatter params
#define NPB 512                         // nodes per bucket (pow2)
#define BSH 9                           // log2(NPB)
#define NBUCK ((NN + NPB - 1) / NPB)    // 196
#define BIN_CHUNK 4096                  // edges per bin block (16/thread)

typedef _Float16 f16x8 __attribute__((ext_vector_type(8)));
typedef float f32x4 __attribute__((ext_vector_type(4)));

__device__ __forceinline__ float eluf(float x) { return x > 0.0f ? x : expm1f(x); }

// ================= CSR build =================

__global__ void count_edges_v2(const int* __restrict__ dst, int* __restrict__ counts) {
    int i = blockIdx.x * blockDim.x + threadIdx.x;
    if (i < EE) atomicAdd(&counts[dst[i]], 1);
}

__global__ void scan_block_v2(const int* __restrict__ counts, int* __restrict__ rp,
                              int* __restrict__ partial, float* __restrict__ dinv) {
    __shared__ int sm[256];
    const int t = threadIdx.x;
    const int base = blockIdx.x * 1024 + t * 4;
    int v0 = 0, v1 = 0, v2 = 0, v3 = 0;
    if (base + 0 < NN) v0 = counts[base + 0];
    if (base + 1 < NN) v1 = counts[base + 1];
    if (base + 2 < NN) v2 = counts[base + 2];
    if (base + 3 < NN) v3 = counts[base + 3];
    if (base + 0 < NN) dinv[base + 0] = rsqrtf((float)(v0 + 1));
    if (base + 1 < NN) dinv[base + 1] = rsqrtf((float)(v1 + 1));
    if (base + 2 < NN) dinv[base + 2] = rsqrtf((float)(v2 + 1));
    if (base + 3 < NN) dinv[base + 3] = rsqrtf((float)(v3 + 1));
    const int s = v0 + v1 + v2 + v3;
    sm[t] = s;
    __syncthreads();
    for (int off = 1; off < 256; off <<= 1) {
        int x = 0;
        if (t >= off) x = sm[t - off];
        __syncthreads();
        if (t >= off) sm[t] += x;
        __syncthreads();
    }
    int excl = sm[t] - s;
    if (t == 255) partial[blockIdx.x] = sm[255];
    if (base + 0 < NN) rp[base + 0] = excl;
    excl += v0;
    if (base + 1 < NN) rp[base + 1] = excl;
    excl += v1;
    if (base + 2 < NN) rp[base + 2] = excl;
    excl += v2;
    if (base + 3 < NN) rp[base + 3] = excl;
}

__global__ void scan_top_v2(int* partial) {
    __shared__ int sm[128];
    const int t = threadIdx.x;
    const int v = (t < NBLK) ? partial[t] : 0;
    sm[t] = v;
    __syncthreads();
    for (int off = 1; off < 128; off <<= 1) {
        int x = 0;
        if (t >= off) x = sm[t - off];
        __syncthreads();
        if (t >= off) sm[t] += x;
        __syncthreads();
    }
    if (t < NBLK) partial[t] = sm[t] - v;  // exclusive
}

__global__ void scan_add_v2(int* rp, const int* __restrict__ partial) {
    const int i = blockIdx.x * blockDim.x + threadIdx.x;
    if (i < NN) rp[i] += partial[i >> 10];
    else if (i == NN) rp[NN] = EE;
}

// ================= binned scatter =================
// R10: scatter_v2 wrote 107MB HBM for a 6.4MB payload. Two-phase binning
// keeps writes in hot windows. Measured R2: saved ~45us net.

__global__ __launch_bounds__(256) void bin_edges_v1(const int* __restrict__ src,
                                                    const int* __restrict__ dst,
                                                    const int* __restrict__ rp,
                                                    int* __restrict__ bfill,
                                                    unsigned* __restrict__ tmp) {
    __shared__ int hist[NBUCK];
    __shared__ int basei[NBUCK];
    __shared__ int rpb[NBUCK];
    __shared__ int cur[NBUCK];
    const int t = threadIdx.x;
    const int e0 = blockIdx.x * BIN_CHUNK;
    for (int b = t; b < NBUCK; b += 256) {
        hist[b] = 0;
        cur[b] = 0;
    }
    __syncthreads();
    int myd[16];
#pragma unroll
    for (int i = 0; i < 16; ++i) {
        const int e = e0 + i * 256 + t;
        int d = -1;
        if (e < EE) {
            d = dst[e];
            atomicAdd(&hist[d >> BSH], 1);
        }
        myd[i] = d;
    }
    __syncthreads();
    for (int b = t; b < NBUCK; b += 256) {
        const int h = hist[b];
        basei[b] = h ? atomicAdd(&bfill[b], h) : 0;
        rpb[b] = rp[b << BSH];
    }
    __syncthreads();
#pragma unroll
    for (int i = 0; i < 16; ++i) {
        const int e = e0 + i * 256 + t;
        if (e < EE) {
            const int d = myd[i];
            const int b = d >> BSH;
            const int slot = atomicAdd(&cur[b], 1);
            tmp[rpb[b] + basei[b] + slot] =
                ((unsigned)(d & (NPB - 1)) << 17) | (unsigned)src[e];
        }
    }
}

__global__ __launch_bounds__(512) void unbin_v1(const unsigned* __restrict__ tmp,
                                                const int* __restrict__ rp,
                                                int* __restrict__ col) {
    __shared__ int lrp[NPB];
    __shared__ int lfill[NPB];
    const int t = threadIdx.x;
    const int node0 = blockIdx.x << BSH;
    const int nodes = (NN - node0 < NPB) ? (NN - node0) : NPB;
    for (int i = t; i < nodes; i += 512) {
        lrp[i] = rp[node0 + i];
        lfill[i] = 0;
    }
    __syncthreads();
    const int lo = rp[node0];
    const int hi = rp[node0 + nodes];
    for (int e = lo + t; e < hi; e += 512) {
        const unsigned v = tmp[e];
        const int s = (int)(v & 0x1FFFFu);
        const int doff = (int)(v >> 17);
        const int pos = lrp[doff] + atomicAdd(&lfill[doff], 1);
        col[pos] = s;
    }
}

// zero sentinel row NN of both fp16 gather buffers (masked lanes gather row NN)
__global__ void init_sent_v2(__half* a, __half* b) {
    const int t = threadIdx.x;
    if (t < 64) a[(size_t)NN * HH + t] = __float2half(0.f);
    else b[(size_t)NN * HH + (t - 64)] = __float2half(0.f);
}

// w_in [256][64] fp32 -> wt [64][256] fp16 (transposed, for MFMA B-fragments)
__global__ void conv_w_v1(const float* __restrict__ w, __half* __restrict__ wt) {
    const int t = threadIdx.x;  // 256
    const int c = t & 63;
    const int k0 = (t >> 6) * 64;
    for (int k = 0; k < 64; ++k)
        wt[(size_t)c * 256 + k0 + k] = __float2half(w[(size_t)(k0 + k) * 64 + c]);
}

// per-layer (beta_l * W_l)^T as fp16: btab[l][c][k] = beta_l * W_l[k][c]
// identity term added exactly in fp32 in the fused epilogue.
__global__ void conv_wbl_v1(const float* __restrict__ w_layers, __half* __restrict__ btab) {
    const int l = blockIdx.x;
    const float beta = logf(1.0f / (float)(l + 1) + 1.0f);
    const float* W = w_layers + (size_t)l * 64 * 64;
    __half* wt = btab + (size_t)l * 64 * 64;
    const int t = threadIdx.x;     // 256
    const int c = t & 63;          // output col
    const int k0 = (t >> 6) * 16;  // 16 k each
    for (int k = k0; k < k0 + 16; ++k)
        wt[(size_t)c * 64 + k] = __float2half(beta * W[(size_t)k * 64 + c]);
}

// ================= fused layer v3: agg -> LDS -> MFMA -> elu =================
// R15 (verified R7: -75us): fusion removed the 51MB/layer sbuf round-trip.
// R16: (a) x0 residual read fp32->fp16 (-12.8MB/layer; error ~2.4e-4*0.5/layer
// through the (1-b) passthrough, ~2e-3 at output, 15x under absmax), (b) gather
// MLP 4->8 rows in flight/lane (agg phase is latency-bound at 24 waves/CU).
// VGPR live ~75 under the 85 cap (6 blk/CU); fused WRITE_SIZE jump = spill =
// revert unroll.

__global__ __launch_bounds__(256, 6) void fused_layer_v3(
    const int* __restrict__ rp, const int* __restrict__ col, const float* __restrict__ dinv,
    const __half* __restrict__ hin, const __half* __restrict__ x0f,
    const __half* __restrict__ wt, float obeta,
    __half* __restrict__ out16, float* __restrict__ out32, int w32) {
    __shared__ float sa[64][68];
    const int t = threadIdx.x;
    const int row0 = blockIdx.x * 64;
    const int lane = t & 63;
    const int w = t >> 6;            // wave 0..3
    const int g = lane >> 3;         // group 0..7
    const int fc = (lane & 7) << 3;  // feature chunk base

    // ---- agg phase: wave w covers rows [w*16, w*16+16), 8 nodes per pass ----
#pragma unroll
    for (int pass = 0; pass < 2; ++pass) {
        const int lrow = w * 16 + pass * 8 + g;
        const int node = row0 + lrow;
        float acc[8] = {};
        if (node < NN) {
            const int start = rp[node], end = rp[node + 1];
            for (int e = start; e < end; e += 8) {
                int cc[8];
#pragma unroll
                for (int i = 0; i < 8; ++i)
                    cc[i] = (e + i < end) ? col[e + i] : NN;  // row NN all-zero
                float4 rr[8];
#pragma unroll
                for (int i = 0; i < 8; ++i)
                    rr[i] = *(const float4*)(hin + ((size_t)cc[i] << 6) + fc);
#pragma unroll
                for (int i = 0; i < 8; ++i) {
                    const __half2* h2 = (const __half2*)&rr[i];
#pragma unroll
                    for (int q = 0; q < 4; ++q) {
                        const float2 f = __half22float2(h2[q]);
                        acc[2 * q] += f.x;
                        acc[2 * q + 1] += f.y;
                    }
                }
            }
            float4 r = *(const float4*)(hin + ((size_t)node << 6) + fc);
            const __half2* hh = (const __half2*)&r;
#pragma unroll
            for (int q = 0; q < 4; ++q) {
                const float2 f = __half22float2(hh[q]);
                acc[2 * q] += f.x;
                acc[2 * q + 1] += f.y;
            }
            const float di = dinv[node];
            // x0 residual (fp16, 16B = 8 features)
            const float4 xv4 = *(const float4*)(x0f + ((size_t)node << 6) + fc);
            const __half2* xh = (const __half2*)&xv4;
            const float2 x0a = __half22float2(xh[0]);
            const float2 x0b = __half22float2(xh[1]);
            const float2 x0c = __half22float2(xh[2]);
            const float2 x0d = __half22float2(xh[3]);
            float4 oa, ob;
            oa.x = 0.5f * fmaf(di, acc[0], x0a.x);
            oa.y = 0.5f * fmaf(di, acc[1], x0a.y);
            oa.z = 0.5f * fmaf(di, acc[2], x0b.x);
            oa.w = 0.5f * fmaf(di, acc[3], x0b.y);
            ob.x = 0.5f * fmaf(di, acc[4], x0c.x);
            ob.y = 0.5f * fmaf(di, acc[5], x0c.y);
            ob.z = 0.5f * fmaf(di, acc[6], x0d.x);
            ob.w = 0.5f * fmaf(di, acc[7], x0d.y);
            *(float4*)&sa[lrow][fc] = oa;
            *(float4*)&sa[lrow][fc + 4] = ob;
        } else {
            *(float4*)&sa[lrow][fc] = make_float4(0.f, 0.f, 0.f, 0.f);
            *(float4*)&sa[lrow][fc + 4] = make_float4(0.f, 0.f, 0.f, 0.f);
        }
    }
    __syncthreads();

    // ---- GEMM phase (lgemm_v5 body): o = b*(s@W) + (1-b)*s ----
    const int la = lane & 15, lg = lane >> 4;
    f32x4 acc2[4] = {};
    const float* arow = &sa[w * 16 + la][0];
#pragma unroll
    for (int kc = 0; kc < 2; ++kc) {
        const int k0 = kc * 32 + lg * 8;
        const float4 s0 = *(const float4*)&arow[k0];
        const float4 s1 = *(const float4*)&arow[k0 + 4];
        f16x8 a;
        a[0] = (_Float16)s0.x; a[1] = (_Float16)s0.y;
        a[2] = (_Float16)s0.z; a[3] = (_Float16)s0.w;
        a[4] = (_Float16)s1.x; a[5] = (_Float16)s1.y;
        a[6] = (_Float16)s1.z; a[7] = (_Float16)s1.w;
#pragma unroll
        for (int tt = 0; tt < 4; ++tt) {
            const f16x8 b = *(const f16x8*)&wt[(size_t)(la + 16 * tt) * 64 + k0];
            acc2[tt] = __builtin_amdgcn_mfma_f32_16x16x32_f16(a, b, acc2[tt], 0, 0, 0);
        }
    }

    // epilogue: o = acc + (1-beta)*s (exact fp32 identity); h = elu(o)+o
#pragma unroll
    for (int i = 0; i < 4; ++i) {
        const int lr = w * 16 + lg * 4 + i;
        const int r = row0 + lr;
        if (r >= NN) continue;
        const float dv = dinv[r];
#pragma unroll
        for (int tt = 0; tt < 4; ++tt) {
            const int c = la + 16 * tt;
            const float o = acc2[tt][i] + obeta * sa[lr][c];
            const float h = eluf(o) + o;
            out16[(size_t)r * 64 + c] = __float2half(h * dv);
            if (w32) out32[(size_t)r * 64 + c] = h;
        }
    }
}

// ================= MFMA input GEMM v3: x0 emitted as fp16 =================
// R6: 71us floor, occupancy/ALU fixes exhausted; R16: cut write bytes
// (38.4 -> 25.6MB): x0 copy now fp16 (only consumer is fused agg residual).

__global__ __launch_bounds__(256, 6) void mgemm_in_v3(
    const float* __restrict__ A, const __half* __restrict__ wt,
    const float* __restrict__ bias, const float* __restrict__ dinvp,
    __half* __restrict__ x0f, __half* __restrict__ out16) {
    __shared__ __half sh[64][136];
    const int t = threadIdx.x;
    const int row0 = blockIdx.x * 64;
    const int lane = t & 63;
    const int w = t >> 6;  // wave 0..3 -> rows [w*16, w*16+16)
    const int la = lane & 15, lg = lane >> 4;
    f32x4 acc[4] = {};

#pragma unroll
    for (int kh = 0; kh < 2; ++kh) {
#pragma unroll
        for (int i = 0; i < 8; ++i) {
            const int linear = t + i * 256;  // 0..2047, 32 float4 per row
            const int r = linear >> 5;
            const int q = linear & 31;
            const int grow = row0 + r;
            float4 v = make_float4(0.f, 0.f, 0.f, 0.f);
            if (grow < NN) v = *(const float4*)&A[(size_t)grow * 256 + kh * 128 + q * 4];
            __half2* dst = (__half2*)&sh[r][q * 4];
            dst[0] = __floats2half2_rn(v.x, v.y);
            dst[1] = __floats2half2_rn(v.z, v.w);
        }
        __syncthreads();
        const __half* arow = &sh[w * 16 + la][0];
#pragma unroll
        for (int kc = 0; kc < 4; ++kc) {
            const int k0 = kc * 32 + lg * 8;
            const f16x8 a = *(const f16x8*)&arow[k0];
#pragma unroll
            for (int tt = 0; tt < 4; ++tt) {
                const f16x8 b = *(const f16x8*)&wt[(size_t)(la + 16 * tt) * 256 + kh * 128 + k0];
                acc[tt] = __builtin_amdgcn_mfma_f32_16x16x32_f16(a, b, acc[tt], 0, 0, 0);
            }
        }
        __syncthreads();
    }

#pragma unroll
    for (int i = 0; i < 4; ++i) {
        const int r = row0 + w * 16 + lg * 4 + i;
        if (r >= NN) continue;
        const float dv = dinvp[r];
#pragma unroll
        for (int tt = 0; tt < 4; ++tt) {
            const int c = la + 16 * tt;
            float o = acc[tt][i] + bias[c];
            o = eluf(o);
            x0f[(size_t)r * 64 + c] = __float2half(o);
            out16[(size_t)r * 64 + c] = __float2half(o * dv);
        }
    }
}

// ================= dense GEMM for output layer (R2-proven shape) =================
// MODE 2: out32 = A@B + bias    (KTOT=64)

template <int KTOT, int MODE>
__global__ __launch_bounds__(256, 4) void gemm_v2(const float* __restrict__ A,
                                                  const float* __restrict__ B,
                                                  const float* __restrict__ bias,
                                                  const float* __restrict__ dinvp,
                                                  float* __restrict__ out32,
                                                  __half* __restrict__ out16) {
    __shared__ float ss[64][68];
    __shared__ float ws[64][64];
    const int t = threadIdx.x;
    const int row0 = blockIdx.x * 64;
    const int tx = t & 15, ty = t >> 4;
    float acc[4][4] = {};

    for (int kc = 0; kc < KTOT; kc += 64) {
#pragma unroll
        for (int i = 0; i < 4; ++i) {
            const int linear = t + i * 256;
            const int r = linear >> 4, q = linear & 15;
            const int grow = row0 + r;
            float4 v = make_float4(0.f, 0.f, 0.f, 0.f);
            if (grow < NN) v = *(const float4*)&A[(size_t)grow * KTOT + kc + q * 4];
            *(float4*)&ss[r][q * 4] = v;
        }
#pragma unroll
        for (int i = 0; i < 4; ++i) {
            const int linear = t + i * 256;
            const int r = linear >> 4, q = linear & 15;
            *(float4*)&ws[r][q * 4] = *(const float4*)&B[(size_t)(kc + r) * 64 + q * 4];
        }
        __syncthreads();
#pragma unroll 4
        for (int k = 0; k < 64; k += 4) {
            float4 af[4], bf[4];
            af[0] = *(const float4*)&ss[ty * 4 + 0][k];
            af[1] = *(const float4*)&ss[ty * 4 + 1][k];
            af[2] = *(const float4*)&ss[ty * 4 + 2][k];
            af[3] = *(const float4*)&ss[ty * 4 + 3][k];
            bf[0] = *(const float4*)&ws[k + 0][tx * 4];
            bf[1] = *(const float4*)&ws[k + 1][tx * 4];
            bf[2] = *(const float4*)&ws[k + 2][tx * 4];
            bf[3] = *(const float4*)&ws[k + 3][tx * 4];
            const float* A4 = (const float*)af;
            const float* B4 = (const float*)bf;
#pragma unroll
            for (int i = 0; i < 4; ++i)
#pragma unroll
                for (int kk = 0; kk < 4; ++kk)
#pragma unroll
                    for (int j = 0; j < 4; ++j)
                        acc[i][j] = fmaf(A4[i * 4 + kk], B4[kk * 4 + j], acc[i][j]);
        }
        __syncthreads();
    }

#pragma unroll
    for (int i = 0; i < 4; ++i) {
        const int r = row0 + ty * 4 + i;
        if (r >= NN) continue;
        float4 o;
        float* op = (float*)&o;
#pragma unroll
        for (int j = 0; j < 4; ++j) {
            float xv = acc[i][j] + bias[tx * 4 + j];
            if (MODE == 0) xv = eluf(xv);
            op[j] = xv;
        }
        *(float4*)&out32[(size_t)r * 64 + tx * 4] = o;
        if (MODE == 0) {
            const float dv = dinvp[r];
            __half2* hp = (__half2*)&out16[(size_t)r * 64 + tx * 4];
            hp[0] = __floats2half2_rn(o.x * dv, o.y * dv);
            hp[1] = __floats2half2_rn(o.z * dv, o.w * dv);
        }
    }
}

// ================= launch =================

extern "C" void kernel_launch(void* const* d_in, const int* in_sizes, int n_in, void* d_out,
                              int out_size, void* d_ws, size_t ws_size, hipStream_t stream) {
    const float* x = (const float*)d_in[0];
    const int* ei = (const int*)d_in[1];
    const float* w_in = (const float*)d_in[2];
    const float* b_in = (const float*)d_in[3];
    const float* w_layers = (const float*)d_in[4];
    const float* w_out = (const float*)d_in[5];
    const float* b_out = (const float*)d_in[6];
    float* out = (float*)d_out;

    char* p = (char*)d_ws;
    auto alloc = [&](size_t bytes) -> char* {
        char* r = p;
        p += (bytes + 255) & ~(size_t)255;
        return r;
    };
    int* counts = (int*)alloc((size_t)NN * 4);
    int* bfill = (int*)alloc((size_t)NBUCK * 4);
    int* rp = (int*)alloc((size_t)(NN + 1) * 4);
    int* partial = (int*)alloc(128 * 4);
    float* dinv = (float*)alloc((size_t)NN * 4);
    int* colA = (int*)alloc((size_t)EE * 4);
    unsigned* tmp = (unsigned*)alloc((size_t)EE * 4);         // binned packed edges
    __half* x0f = (__half*)alloc((size_t)NN * HH * 2);        // fp16 residual (unscaled)
    __half* x0h = (__half*)alloc((size_t)(NN + 1) * HH * 2);  // scaled gather buf A
    __half* hA = (__half*)alloc((size_t)(NN + 1) * HH * 2);   // scaled gather buf B
    float* sbuf = (float*)alloc((size_t)NN * HH * 4);         // final fp32 h (last layer)
    __half* wt = (__half*)alloc((size_t)64 * 256 * 2);        // w_in^T fp16
    __half* btab = (__half*)alloc((size_t)LL * 64 * 64 * 2);  // per-layer (beta*W)^T fp16

    const int* srcA = ei;
    const int* dstA = ei + EE;

    hipMemsetAsync(counts, 0, (size_t)NN * 4, stream);
    hipMemsetAsync(bfill, 0, (size_t)NBUCK * 4, stream);
    init_sent_v2<<<1, 128, 0, stream>>>(x0h, hA);
    conv_w_v1<<<1, 256, 0, stream>>>(w_in, wt);
    conv_wbl_v1<<<LL, 256, 0, stream>>>(w_layers, btab);
    count_edges_v2<<<(EE + 255) / 256, 256, 0, stream>>>(dstA, counts);
    scan_block_v2<<<NBLK, 256, 0, stream>>>(counts, rp, partial, dinv);
    scan_top_v2<<<1, 128, 0, stream>>>(partial);
    scan_add_v2<<<(NN + 1 + 255) / 256, 256, 0, stream>>>(rp, partial);
    bin_edges_v1<<<(EE + BIN_CHUNK - 1) / BIN_CHUNK, 256, 0, stream>>>(srcA, dstA, rp, bfill,
                                                                       tmp);
    unbin_v1<<<NBUCK, 512, 0, stream>>>(tmp, rp, colA);

    // x0f = half(elu(x @ w_in + b_in));  x0h = half(dinv * x0)   [MFMA]
    mgemm_in_v3<<<(NN + 63) / 64, 256, 0, stream>>>(x, wt, b_in, dinv, x0f, x0h);

    for (int l = 0; l < LL; ++l) {
        const float obeta = 1.0f - (float)log(1.0 / (double)(l + 1) + 1.0);
        const __half* hin = (l & 1) ? hA : x0h;  // l=0 reads x0h
        __half* hout = (l & 1) ? x0h : hA;
        fused_layer_v3<<<(NN + 63) / 64, 256, 0, stream>>>(
            rp, colA, dinv, hin, x0f, btab + (size_t)l * 64 * 64, obeta, hout, sbuf,
            l == LL - 1);
    }
    gemm_v2<64, 2><<<(NN + 63) / 64, 256, 0, stream>>>(sbuf, w_out, b_out, nullptr, out, nullptr);
}